// Round 7
// baseline (718.687 us; speedup 1.0000x reference)
//
#include <hip/hip_runtime.h>
#include <hip/hip_bf16.h>
#include <cstdint>
#include <cstddef>

#define HIDN   512
#define NHEADS 8
#define BATCH  8
#define SLEN   4096
#define TLEN   512
#define SSPLIT 4
#define SCL2   0.18033688f              // 0.125 * log2(e)

typedef __attribute__((ext_vector_type(8))) short   bf16x8;
typedef __attribute__((ext_vector_type(4))) float   f32x4;
typedef unsigned short u16;
typedef unsigned int   u32;

__device__ __forceinline__ u32 pkbf(float a, float b) {        // accurate RNE
    __hip_bfloat162 h = __float22bfloat162_rn(float2{a, b});
    union { __hip_bfloat162 h; u32 u; } un; un.h = h; return un.u;   // a low
}
// fast 3-op pack (round-half-up): v_add, v_add, v_perm
__device__ __forceinline__ u32 pk2(float a, float b) {
    union { float f; u32 u; } ua, ub; ua.f = a; ub.f = b;
    return __builtin_amdgcn_perm(ub.u + 0x8000u, ua.u + 0x8000u, 0x07060302u);
}
__device__ __forceinline__ void gload_lds16(const u16* g, u16* l) {
    __builtin_amdgcn_global_load_lds(
        (const __attribute__((address_space(1))) u32*)g,
        (__attribute__((address_space(3))) u32*)l, 16, 0, 0);
}

// ---------------------------------------------------------------------------
// fp32->bf16 conversion + mask->neg(-1e30) pass.
// float4-unit ranges: X 4194304 | T 524288 | W 262144 | mask 8192 = 4988928
// ---------------------------------------------------------------------------
__global__ __launch_bounds__(256) void cvt_all(
    const float* __restrict__ X, const float* __restrict__ Tg,
    const float* __restrict__ Wq, const float* __restrict__ Wk,
    const float* __restrict__ Wv, const float* __restrict__ Wo,
    const int* __restrict__ mask,
    u16* __restrict__ Xc, u16* __restrict__ Tc, u16* __restrict__ Wc,
    float* __restrict__ negf)
{
    int i4 = blockIdx.x * 256 + threadIdx.x;
    if (i4 >= 4980736) {
        int off = i4 - 4980736;
        int4 mv = ((const int4*)mask)[off];
        float4 nv;
        nv.x = mv.x ? 0.f : -1e30f; nv.y = mv.y ? 0.f : -1e30f;
        nv.z = mv.z ? 0.f : -1e30f; nv.w = mv.w ? 0.f : -1e30f;
        ((float4*)negf)[off] = nv;
        return;
    }
    const float* s; u16* d; long off;
    if (i4 < 4194304)      { s = X;  d = Xc; off = i4; }
    else if (i4 < 4718592) { s = Tg; d = Tc; off = i4 - 4194304; }
    else {
        int wi = i4 - 4718592; int widx = wi >> 16;
        s = (widx == 0) ? Wq : (widx == 1) ? Wk : (widx == 2) ? Wv : Wo;
        d = Wc + widx * 262144; off = wi & 65535;
    }
    float4 v = *(const float4*)(s + off * 4);
    uint2 o; o.x = pkbf(v.x, v.y); o.y = pkbf(v.z, v.w);
    *(uint2*)(d + off * 4) = o;
}

// ---------------------------------------------------------------------------
// GEMM A-orientation: Y = A @ W^T + bias.
// MODE 0: fp32 Y[n*512+o] (out-proj).  MODE 2: bf16 (B,H,dk,seq) = V^T.
// ---------------------------------------------------------------------------
template<int MODE, int SEQ>
__global__ __launch_bounds__(256)
void gemm_bf16(const u16* __restrict__ A, const u16* __restrict__ Bw,
               const float* __restrict__ bias, void* __restrict__ Yv)
{
    __shared__ u16 As[128 * 32];
    __shared__ u16 Bs[128 * 32];
    const int tid = threadIdx.x;
    const int lane = tid & 63, w = tid >> 6;
    const int m = lane & 15, qd = lane >> 4;
    const int wm = w >> 1, wn = w & 1;
    const int m0 = blockIdx.y * 128, n0 = blockIdx.x * 128;

    f32x4 acc[4][4];
#pragma unroll
    for (int i = 0; i < 4; ++i)
#pragma unroll
        for (int j = 0; j < 4; ++j) acc[i][j] = (f32x4){0.f, 0.f, 0.f, 0.f};

    for (int k0 = 0; k0 < HIDN; k0 += 32) {
#pragma unroll
        for (int r = 0; r < 2; ++r) {
            const int f = tid + r * 256;
            const int row = f >> 2, c8 = (f & 3) * 8;
            const int fb = f & ~63;
            gload_lds16(A  + (size_t)(m0 + row) * HIDN + k0 + c8, As + fb * 8);
            gload_lds16(Bw + (size_t)(n0 + row) * HIDN + k0 + c8, Bs + fb * 8);
        }
        __syncthreads();
        bf16x8 af[4], bf[4];
#pragma unroll
        for (int t = 0; t < 4; ++t) {
            af[t] = *(bf16x8*)&As[(64 * wm + 16 * t + m) * 32 + 8 * qd];
            bf[t] = *(bf16x8*)&Bs[(64 * wn + 16 * t + m) * 32 + 8 * qd];
        }
#pragma unroll
        for (int ti = 0; ti < 4; ++ti)
#pragma unroll
            for (int tj = 0; tj < 4; ++tj)
                acc[ti][tj] = __builtin_amdgcn_mfma_f32_16x16x32_bf16(
                    af[ti], bf[tj], acc[ti][tj], 0, 0, 0);
        __syncthreads();
    }

#pragma unroll
    for (int ti = 0; ti < 4; ++ti) {
        const int gr0 = m0 + 64 * wm + 16 * ti + 4 * qd;
#pragma unroll
        for (int tj = 0; tj < 4; ++tj) {
            const int gcol = n0 + 64 * wn + 16 * tj + m;
            const float bv = bias[gcol];
            if (MODE == 0) {
                float* Y = (float*)Yv;
#pragma unroll
                for (int i = 0; i < 4; ++i)
                    Y[(size_t)(gr0 + i) * HIDN + gcol] = acc[ti][tj][i] + bv;
            } else {
                u16* Y = (u16*)Yv;
                const int b = gr0 / SEQ, h = gcol >> 6, d = gcol & 63;
                const int r = gr0 & (SEQ - 1);
                uint2 o;
                o.x = pkbf(acc[ti][tj][0] + bv, acc[ti][tj][1] + bv);
                o.y = pkbf(acc[ti][tj][2] + bv, acc[ti][tj][3] + bv);
                *(uint2*)&Y[(((size_t)(b * 8 + h)) * 64 + d) * SEQ + r] = o;
            }
        }
    }
}

// ---------------------------------------------------------------------------
// GEMM W-orientation (Q,K projections): C[o][sample] = W·X^T + bias,
// coalesced uint2 bf16 stores into (B,H,seq,64).
// ---------------------------------------------------------------------------
template<int SEQ>
__global__ __launch_bounds__(256)
void gemm_wxT(const u16* __restrict__ Wm, const u16* __restrict__ X,
              const float* __restrict__ bias, u16* __restrict__ Y)
{
    __shared__ u16 As[128 * 32];   // W rows (o)
    __shared__ u16 Bs[128 * 32];   // X rows (samples)
    const int tid = threadIdx.x;
    const int lane = tid & 63, w = tid >> 6;
    const int m = lane & 15, qd = lane >> 4;
    const int wm = w >> 1, wn = w & 1;
    const int m0 = blockIdx.y * 128, n0 = blockIdx.x * 128;

    f32x4 acc[4][4];
#pragma unroll
    for (int i = 0; i < 4; ++i)
#pragma unroll
        for (int j = 0; j < 4; ++j) acc[i][j] = (f32x4){0.f, 0.f, 0.f, 0.f};

    for (int k0 = 0; k0 < HIDN; k0 += 32) {
#pragma unroll
        for (int r = 0; r < 2; ++r) {
            const int f = tid + r * 256;
            const int row = f >> 2, c8 = (f & 3) * 8;
            const int fb = f & ~63;
            gload_lds16(Wm + (size_t)(m0 + row) * HIDN + k0 + c8, As + fb * 8);
            gload_lds16(X  + (size_t)(n0 + row) * HIDN + k0 + c8, Bs + fb * 8);
        }
        __syncthreads();
        bf16x8 af[4], bf[4];
#pragma unroll
        for (int t = 0; t < 4; ++t) {
            af[t] = *(bf16x8*)&As[(64 * wm + 16 * t + m) * 32 + 8 * qd];
            bf[t] = *(bf16x8*)&Bs[(64 * wn + 16 * t + m) * 32 + 8 * qd];
        }
#pragma unroll
        for (int ti = 0; ti < 4; ++ti)
#pragma unroll
            for (int tj = 0; tj < 4; ++tj)
                acc[ti][tj] = __builtin_amdgcn_mfma_f32_16x16x32_bf16(
                    af[ti], bf[tj], acc[ti][tj], 0, 0, 0);
        __syncthreads();
    }

#pragma unroll
    for (int ti = 0; ti < 4; ++ti) {
        const int o = m0 + 64 * wm + 16 * ti + 4 * qd;
        const float4 bv = *(const float4*)&bias[o];
        const int h = o >> 6, d0 = o & 63;
#pragma unroll
        for (int tj = 0; tj < 4; ++tj) {
            const int n = n0 + 64 * wn + 16 * tj + m;
            const int b = n / SEQ, r = n & (SEQ - 1);
            uint2 pk;
            pk.x = pkbf(acc[ti][tj][0] + bv.x, acc[ti][tj][1] + bv.y);
            pk.y = pkbf(acc[ti][tj][2] + bv.z, acc[ti][tj][3] + bv.w);
            *(uint2*)&Y[(((size_t)(b * 8 + h)) * SEQ + r) * 64 + d0] = pk;
        }
    }
}

// ---------------------------------------------------------------------------
// Flash attention partial kernel: 512 thr / 8 waves = 2 s-groups (sg) x
// 4 t-waves (tw). Grid (ti=2, si=4, bh=64) = 512 blocks -> 4096 waves
// = 16 waves/CU = 4 waves/EU (launch_bounds (512,4) caps VGPR at 128,
// natural use ~124 -> 2 blocks/CU; LDS 66.5KB x2 = 133KB fits).
// Wave: 64 t (4 strips), 512 s in 64-chunks; r4-proven barrier-free inner
// loop (direct-global frags, max-free exp2 softmax, per-wave XOR-swizzled
// LDS P-relayout).  Epilogue: 2-way sg combine in LDS (2 barriers), then
// sg0 writes fp32 Opart[si] + lpart[si]; attn_combine sums si partials.
// ---------------------------------------------------------------------------
__global__ __launch_bounds__(512, 4)
void attn_fused(const u16* __restrict__ Q, const u16* __restrict__ K,
                const u16* __restrict__ Vt, const float* __restrict__ negf,
                float* __restrict__ Opart, float* __restrict__ lpart)
{
    __shared__ char  Psh[65536];     // 8 waves x 8KB; reused for sg combine
    __shared__ float lsh[4][64];     // sg1 l partials: [tw][ts*16+m]

    const int tid = threadIdx.x;
    const int lane = tid & 63, w = tid >> 6;      // w 0..7
    const int sg = w >> 2, tw = w & 3;
    const int m = lane & 15, qd = lane >> 4;
    const int ti = blockIdx.x, si = blockIdx.y, bh = blockIdx.z;
    const int b = bh >> 3;

    const u16* Qp = Q + ((size_t)bh * TLEN + ti * 256) * 64;
    const u16* Kp = K + (size_t)bh * SLEN * 64;
    const u16* Vp = Vt + (size_t)bh * 64 * SLEN;
    const float* np = negf + (size_t)b * SLEN;

    // per-wave P buffer: row t=m (128B), 8B units XOR-swizzled by m
    const int wb = w * 8192 + m * 128;
    int waddr[4], ra0[2], ra1[2];
#pragma unroll
    for (int st = 0; st < 4; ++st) waddr[st] = wb + (((4 * st + qd) ^ m) << 3);
#pragma unroll
    for (int ks = 0; ks < 2; ++ks) {
        const int u0 = 8 * ks + 2 * qd;
        ra0[ks] = wb + ((u0 ^ m) << 3);
        ra1[ks] = wb + (((u0 + 1) ^ m) << 3);
    }

    bf16x8 qf[4][2];
#pragma unroll
    for (int ts = 0; ts < 4; ++ts)
#pragma unroll
        for (int kh = 0; kh < 2; ++kh)
            qf[ts][kh] = *(const bf16x8*)(Qp + (tw * 64 + ts * 16 + m) * 64 +
                                          32 * kh + 8 * qd);

    f32x4 O[4][4];
#pragma unroll
    for (int ts = 0; ts < 4; ++ts)
#pragma unroll
        for (int dt = 0; dt < 4; ++dt) O[ts][dt] = (f32x4){0.f, 0.f, 0.f, 0.f};
    float lr[4] = {0.f, 0.f, 0.f, 0.f};

    const int s_beg = si * 1024 + sg * 512;
    const u16* kp = Kp + (size_t)(s_beg + m) * 64 + 8 * qd;   // st*1024, kh*32 imm
    const u16* vp0 = Vp + (size_t)m * SLEN + s_beg + 8 * qd;  // ks*32 imm
    const u16* vp1 = vp0 + (size_t)16 * SLEN;
    const u16* vp2 = vp0 + (size_t)32 * SLEN;
    const u16* vp3 = vp0 + (size_t)48 * SLEN;
    const float* npp = np + s_beg + 4 * qd;                   // st*16 imm

#pragma unroll 1
    for (int c = 0; c < 512; c += 64) {
        bf16x8 kf[4][2];
        kf[0][0] = *(const bf16x8*)(kp + 0);
        kf[0][1] = *(const bf16x8*)(kp + 32);
        kf[1][0] = *(const bf16x8*)(kp + 1024);
        kf[1][1] = *(const bf16x8*)(kp + 1056);
        kf[2][0] = *(const bf16x8*)(kp + 2048);
        kf[2][1] = *(const bf16x8*)(kp + 2080);
        kf[3][0] = *(const bf16x8*)(kp + 3072);
        kf[3][1] = *(const bf16x8*)(kp + 3104);
        float4 ng[4];
        ng[0] = *(const float4*)(npp + 0);
        ng[1] = *(const float4*)(npp + 16);
        ng[2] = *(const float4*)(npp + 32);
        ng[3] = *(const float4*)(npp + 48);
        bf16x8 vf[4][2];
        vf[0][0] = *(const bf16x8*)(vp0 + 0);
        vf[0][1] = *(const bf16x8*)(vp0 + 32);
        vf[1][0] = *(const bf16x8*)(vp1 + 0);
        vf[1][1] = *(const bf16x8*)(vp1 + 32);
        vf[2][0] = *(const bf16x8*)(vp2 + 0);
        vf[2][1] = *(const bf16x8*)(vp2 + 32);
        vf[3][0] = *(const bf16x8*)(vp3 + 0);
        vf[3][1] = *(const bf16x8*)(vp3 + 32);

#pragma unroll
        for (int ts = 0; ts < 4; ++ts) {
            f32x4 S[4];
#pragma unroll
            for (int st = 0; st < 4; ++st) {
                f32x4 cc = (f32x4){0.f, 0.f, 0.f, 0.f};
                cc = __builtin_amdgcn_mfma_f32_16x16x32_bf16(kf[st][0], qf[ts][0], cc, 0, 0, 0);
                cc = __builtin_amdgcn_mfma_f32_16x16x32_bf16(kf[st][1], qf[ts][1], cc, 0, 0, 0);
                S[st] = cc;
            }
            float ls = 0.f;
#pragma unroll
            for (int st = 0; st < 4; ++st) {
                const float p0 = __builtin_amdgcn_exp2f(fmaf(S[st][0], SCL2, ng[st].x));
                const float p1 = __builtin_amdgcn_exp2f(fmaf(S[st][1], SCL2, ng[st].y));
                const float p2 = __builtin_amdgcn_exp2f(fmaf(S[st][2], SCL2, ng[st].z));
                const float p3 = __builtin_amdgcn_exp2f(fmaf(S[st][3], SCL2, ng[st].w));
                ls += (p0 + p1) + (p2 + p3);
                *(uint2*)&Psh[waddr[st] + ts * 2048] =
                    make_uint2(pk2(p0, p1), pk2(p2, p3));
            }
            lr[ts] += ls;
#pragma unroll
            for (int ks = 0; ks < 2; ++ks) {
                const uint2 r0 = *(uint2*)&Psh[ra0[ks] + ts * 2048];
                const uint2 r1 = *(uint2*)&Psh[ra1[ks] + ts * 2048];
                union { uint4 u; bf16x8 v; } bu;
                bu.u = make_uint4(r0.x, r0.y, r1.x, r1.y);
                O[ts][0] = __builtin_amdgcn_mfma_f32_16x16x32_bf16(vf[0][ks], bu.v, O[ts][0], 0, 0, 0);
                O[ts][1] = __builtin_amdgcn_mfma_f32_16x16x32_bf16(vf[1][ks], bu.v, O[ts][1], 0, 0, 0);
                O[ts][2] = __builtin_amdgcn_mfma_f32_16x16x32_bf16(vf[2][ks], bu.v, O[ts][2], 0, 0, 0);
                O[ts][3] = __builtin_amdgcn_mfma_f32_16x16x32_bf16(vf[3][ks], bu.v, O[ts][3], 0, 0, 0);
            }
        }
        kp += 4096; vp0 += 64; vp1 += 64; vp2 += 64; vp3 += 64; npp += 64;
    }

    // ---- epilogue: 2-way sg combine in LDS, then Opart/lpart write ----
    float lt[4];
#pragma unroll
    for (int ts = 0; ts < 4; ++ts) {
        float l = lr[ts];
        l += __shfl_xor(l, 16, 64);
        l += __shfl_xor(l, 32, 64);
        lt[ts] = l;
    }
    __syncthreads();                 // all waves done with their Psh regions
    float* combf = (float*)Psh;      // [tw][ts][dt][lane] f32x4
    if (sg == 1) {
#pragma unroll
        for (int ts = 0; ts < 4; ++ts) {
#pragma unroll
            for (int dt = 0; dt < 4; ++dt)
                *(f32x4*)&combf[tw * 4096 + ts * 1024 + dt * 256 + lane * 4] =
                    O[ts][dt];
            if (qd == 0) lsh[tw][ts * 16 + m] = lt[ts];
        }
    }
    __syncthreads();
    if (sg == 0) {
#pragma unroll
        for (int ts = 0; ts < 4; ++ts) {
            const float lsum = lt[ts] + lsh[tw][ts * 16 + m];
            const int t = ti * 256 + tw * 64 + ts * 16 + m;
            float* Ob = Opart + (((size_t)(si * 64 + bh)) * 512 + t) * 64;
#pragma unroll
            for (int dt = 0; dt < 4; ++dt) {
                const f32x4 v = *(f32x4*)&combf[tw * 4096 + ts * 1024 + dt * 256 + lane * 4];
                f32x4 o = O[ts][dt];
                o[0] += v[0]; o[1] += v[1]; o[2] += v[2]; o[3] += v[3];
                *(f32x4*)&Ob[16 * dt + 4 * qd] = o;
            }
            if (qd == 0)
                lpart[((size_t)(si * 64 + bh)) * 512 + t] = lsum;
        }
    }
}

// ---------------------------------------------------------------------------
// Combine split-S partials: ctx(B,T,512) bf16 = (sum O)/(sum l).
// ---------------------------------------------------------------------------
__global__ __launch_bounds__(256)
void attn_combine(const float* __restrict__ Opart, const float* __restrict__ lpart,
                  u16* __restrict__ ctx)
{
    const int gid = blockIdx.x * 256 + threadIdx.x;
    const int d4 = gid & 15, t = (gid >> 4) & 511, bh = gid >> 13;
    const int b = bh >> 3, h = bh & 7;
    float4 o = {0.f, 0.f, 0.f, 0.f}; float l = 0.f;
#pragma unroll
    for (int si = 0; si < SSPLIT; ++si) {
        const size_t base = ((size_t)(si * 64 + bh)) * 512 + t;
        l += lpart[base];
        const float4 v = *(const float4*)(Opart + base * 64 + d4 * 4);
        o.x += v.x; o.y += v.y; o.z += v.z; o.w += v.w;
    }
    const float r = 1.f / l;
    uint2 pk; pk.x = pkbf(o.x * r, o.y * r); pk.y = pkbf(o.z * r, o.w * r);
    *(uint2*)&ctx[((size_t)(b * 512 + t)) * 512 + h * 64 + d4 * 4] = pk;
}

// ---------------------------------------------------------------------------
extern "C" void kernel_launch(void* const* d_in, const int* in_sizes, int n_in,
                              void* d_out, int out_size, void* d_ws, size_t ws_size,
                              hipStream_t stream)
{
    const float* inputs  = (const float*)d_in[0];
    const float* targets = (const float*)d_in[1];
    const int*   mask    = (const int*)d_in[2];
    const float* Wq = (const float*)d_in[3];
    const float* bq = (const float*)d_in[4];
    const float* Wk = (const float*)d_in[5];
    const float* bk = (const float*)d_in[6];
    const float* Wv = (const float*)d_in[7];
    const float* bv = (const float*)d_in[8];
    const float* Wo = (const float*)d_in[9];
    const float* bo = (const float*)d_in[10];

    char* ws = (char*)d_ws;
    u16*   Xc    = (u16*)(ws);                            // 33,554,432 B
    u16*   Tc    = (u16*)(ws + 33554432);                 //  4,194,304
    u16*   Wc    = (u16*)(ws + 37748736);                 //  2,097,152
    float* negf  = (float*)(ws + 39845888);               //    131,072
    u16*   Qws   = (u16*)(ws + 39976960);                 //  4,194,304
    u16*   Kws   = (u16*)(ws + 44171264);                 // 33,554,432
    u16*   Vtws  = (u16*)(ws + 77725696);                 // 33,554,432
    u16*   Cws   = (u16*)(ws + 111280128);                //  4,194,304
    float* Opart = (float*)(ws + 115474432);              // 33,554,432
    float* lpart = (float*)(ws + 149028864);              //    524,288

    cvt_all<<<19488, 256, 0, stream>>>(inputs, targets, Wq, Wk, Wv, Wo, mask,
                                       Xc, Tc, Wc, negf);

    gemm_wxT<TLEN><<<dim3(32, 4),  256, 0, stream>>>(Wc,          Tc, bq, Qws);
    gemm_wxT<SLEN><<<dim3(256, 4), 256, 0, stream>>>(Wc + 262144, Xc, bk, Kws);
    gemm_bf16<2, SLEN><<<dim3(4, 256), 256, 0, stream>>>(Xc, Wc + 524288, bv, Vtws);

    attn_fused<<<dim3(2, 4, 64), 512, 0, stream>>>(Qws, Kws, Vtws, negf,
                                                   Opart, lpart);
    attn_combine<<<2048, 256, 0, stream>>>(Opart, lpart, Cws);

    gemm_bf16<0, TLEN><<<dim3(4, 32), 256, 0, stream>>>(Cws, Wc + 786432, bo,
                                                        (float*)d_out);
}

// Round 8
// 308.065 us; speedup vs baseline: 2.3329x; 2.3329x over previous
//
#include <hip/hip_runtime.h>
#include <hip/hip_bf16.h>
#include <cstdint>
#include <cstddef>

#define HIDN   512
#define NHEADS 8
#define BATCH  8
#define SLEN   4096
#define TLEN   512
#define SSPLIT 4
#define SCL2   0.18033688f              // 0.125 * log2(e)

typedef __attribute__((ext_vector_type(8))) short   bf16x8;
typedef __attribute__((ext_vector_type(4))) float   f32x4;
typedef unsigned short u16;
typedef unsigned int   u32;

__device__ __forceinline__ u32 pkbf(float a, float b) {        // accurate RNE
    __hip_bfloat162 h = __float22bfloat162_rn(float2{a, b});
    union { __hip_bfloat162 h; u32 u; } un; un.h = h; return un.u;   // a low
}
// fast 3-op pack (round-half-up): v_add, v_add, v_perm
__device__ __forceinline__ u32 pk2(float a, float b) {
    union { float f; u32 u; } ua, ub; ua.f = a; ub.f = b;
    return __builtin_amdgcn_perm(ub.u + 0x8000u, ua.u + 0x8000u, 0x07060302u);
}
__device__ __forceinline__ void gload_lds16(const u16* g, u16* l) {
    __builtin_amdgcn_global_load_lds(
        (const __attribute__((address_space(1))) u32*)g,
        (__attribute__((address_space(3))) u32*)l, 16, 0, 0);
}

// ---------------------------------------------------------------------------
// fp32->bf16 conversion + mask->neg(-1e30) pass.
// float4-unit ranges: X 4194304 | T 524288 | W 262144 | mask 8192 = 4988928
// ---------------------------------------------------------------------------
__global__ __launch_bounds__(256) void cvt_all(
    const float* __restrict__ X, const float* __restrict__ Tg,
    const float* __restrict__ Wq, const float* __restrict__ Wk,
    const float* __restrict__ Wv, const float* __restrict__ Wo,
    const int* __restrict__ mask,
    u16* __restrict__ Xc, u16* __restrict__ Tc, u16* __restrict__ Wc,
    float* __restrict__ negf)
{
    int i4 = blockIdx.x * 256 + threadIdx.x;
    if (i4 >= 4980736) {
        int off = i4 - 4980736;
        int4 mv = ((const int4*)mask)[off];
        float4 nv;
        nv.x = mv.x ? 0.f : -1e30f; nv.y = mv.y ? 0.f : -1e30f;
        nv.z = mv.z ? 0.f : -1e30f; nv.w = mv.w ? 0.f : -1e30f;
        ((float4*)negf)[off] = nv;
        return;
    }
    const float* s; u16* d; long off;
    if (i4 < 4194304)      { s = X;  d = Xc; off = i4; }
    else if (i4 < 4718592) { s = Tg; d = Tc; off = i4 - 4194304; }
    else {
        int wi = i4 - 4718592; int widx = wi >> 16;
        s = (widx == 0) ? Wq : (widx == 1) ? Wk : (widx == 2) ? Wv : Wo;
        d = Wc + widx * 262144; off = wi & 65535;
    }
    float4 v = *(const float4*)(s + off * 4);
    uint2 o; o.x = pkbf(v.x, v.y); o.y = pkbf(v.z, v.w);
    *(uint2*)(d + off * 4) = o;
}

// ---------------------------------------------------------------------------
// GEMM A-orientation: Y = A @ W^T + bias.
// MODE 0: fp32 Y[n*512+o] (out-proj).  MODE 2: bf16 (B,H,dk,seq) = V^T.
// ---------------------------------------------------------------------------
template<int MODE, int SEQ>
__global__ __launch_bounds__(256)
void gemm_bf16(const u16* __restrict__ A, const u16* __restrict__ Bw,
               const float* __restrict__ bias, void* __restrict__ Yv)
{
    __shared__ u16 As[128 * 32];
    __shared__ u16 Bs[128 * 32];
    const int tid = threadIdx.x;
    const int lane = tid & 63, w = tid >> 6;
    const int m = lane & 15, qd = lane >> 4;
    const int wm = w >> 1, wn = w & 1;
    const int m0 = blockIdx.y * 128, n0 = blockIdx.x * 128;

    f32x4 acc[4][4];
#pragma unroll
    for (int i = 0; i < 4; ++i)
#pragma unroll
        for (int j = 0; j < 4; ++j) acc[i][j] = (f32x4){0.f, 0.f, 0.f, 0.f};

    for (int k0 = 0; k0 < HIDN; k0 += 32) {
#pragma unroll
        for (int r = 0; r < 2; ++r) {
            const int f = tid + r * 256;
            const int row = f >> 2, c8 = (f & 3) * 8;
            const int fb = f & ~63;
            gload_lds16(A  + (size_t)(m0 + row) * HIDN + k0 + c8, As + fb * 8);
            gload_lds16(Bw + (size_t)(n0 + row) * HIDN + k0 + c8, Bs + fb * 8);
        }
        __syncthreads();
        bf16x8 af[4], bf[4];
#pragma unroll
        for (int t = 0; t < 4; ++t) {
            af[t] = *(bf16x8*)&As[(64 * wm + 16 * t + m) * 32 + 8 * qd];
            bf[t] = *(bf16x8*)&Bs[(64 * wn + 16 * t + m) * 32 + 8 * qd];
        }
#pragma unroll
        for (int ti = 0; ti < 4; ++ti)
#pragma unroll
            for (int tj = 0; tj < 4; ++tj)
                acc[ti][tj] = __builtin_amdgcn_mfma_f32_16x16x32_bf16(
                    af[ti], bf[tj], acc[ti][tj], 0, 0, 0);
        __syncthreads();
    }

#pragma unroll
    for (int ti = 0; ti < 4; ++ti) {
        const int gr0 = m0 + 64 * wm + 16 * ti + 4 * qd;
#pragma unroll
        for (int tj = 0; tj < 4; ++tj) {
            const int gcol = n0 + 64 * wn + 16 * tj + m;
            const float bv = bias[gcol];
            if (MODE == 0) {
                float* Y = (float*)Yv;
#pragma unroll
                for (int i = 0; i < 4; ++i)
                    Y[(size_t)(gr0 + i) * HIDN + gcol] = acc[ti][tj][i] + bv;
            } else {
                u16* Y = (u16*)Yv;
                const int b = gr0 / SEQ, h = gcol >> 6, d = gcol & 63;
                const int r = gr0 & (SEQ - 1);
                uint2 o;
                o.x = pkbf(acc[ti][tj][0] + bv, acc[ti][tj][1] + bv);
                o.y = pkbf(acc[ti][tj][2] + bv, acc[ti][tj][3] + bv);
                *(uint2*)&Y[(((size_t)(b * 8 + h)) * 64 + d) * SEQ + r] = o;
            }
        }
    }
}

// ---------------------------------------------------------------------------
// GEMM W-orientation (Q,K projections): C[o][sample] = W·X^T + bias,
// coalesced uint2 bf16 stores into (B,H,seq,64).
// ---------------------------------------------------------------------------
template<int SEQ>
__global__ __launch_bounds__(256)
void gemm_wxT(const u16* __restrict__ Wm, const u16* __restrict__ X,
              const float* __restrict__ bias, u16* __restrict__ Y)
{
    __shared__ u16 As[128 * 32];   // W rows (o)
    __shared__ u16 Bs[128 * 32];   // X rows (samples)
    const int tid = threadIdx.x;
    const int lane = tid & 63, w = tid >> 6;
    const int m = lane & 15, qd = lane >> 4;
    const int wm = w >> 1, wn = w & 1;
    const int m0 = blockIdx.y * 128, n0 = blockIdx.x * 128;

    f32x4 acc[4][4];
#pragma unroll
    for (int i = 0; i < 4; ++i)
#pragma unroll
        for (int j = 0; j < 4; ++j) acc[i][j] = (f32x4){0.f, 0.f, 0.f, 0.f};

    for (int k0 = 0; k0 < HIDN; k0 += 32) {
#pragma unroll
        for (int r = 0; r < 2; ++r) {
            const int f = tid + r * 256;
            const int row = f >> 2, c8 = (f & 3) * 8;
            const int fb = f & ~63;
            gload_lds16(Wm + (size_t)(m0 + row) * HIDN + k0 + c8, As + fb * 8);
            gload_lds16(X  + (size_t)(n0 + row) * HIDN + k0 + c8, Bs + fb * 8);
        }
        __syncthreads();
        bf16x8 af[4], bf[4];
#pragma unroll
        for (int t = 0; t < 4; ++t) {
            af[t] = *(bf16x8*)&As[(64 * wm + 16 * t + m) * 32 + 8 * qd];
            bf[t] = *(bf16x8*)&Bs[(64 * wn + 16 * t + m) * 32 + 8 * qd];
        }
#pragma unroll
        for (int ti = 0; ti < 4; ++ti)
#pragma unroll
            for (int tj = 0; tj < 4; ++tj)
                acc[ti][tj] = __builtin_amdgcn_mfma_f32_16x16x32_bf16(
                    af[ti], bf[tj], acc[ti][tj], 0, 0, 0);
        __syncthreads();
    }

#pragma unroll
    for (int ti = 0; ti < 4; ++ti) {
        const int o = m0 + 64 * wm + 16 * ti + 4 * qd;
        const float4 bv = *(const float4*)&bias[o];
        const int h = o >> 6, d0 = o & 63;
#pragma unroll
        for (int tj = 0; tj < 4; ++tj) {
            const int n = n0 + 64 * wn + 16 * tj + m;
            const int b = n / SEQ, r = n & (SEQ - 1);
            uint2 pk;
            pk.x = pkbf(acc[ti][tj][0] + bv.x, acc[ti][tj][1] + bv.y);
            pk.y = pkbf(acc[ti][tj][2] + bv.z, acc[ti][tj][3] + bv.w);
            *(uint2*)&Y[(((size_t)(b * 8 + h)) * SEQ + r) * 64 + d0] = pk;
        }
    }
}

// ---------------------------------------------------------------------------
// Flash attention partial kernel: 512 thr / 8 waves = 2 s-groups (sg) x
// 4 t-waves (tw). Grid (ti=2, si=4, bh=64) = 512 blocks -> 4096 waves.
// launch_bounds (512,2): empirically arg caps VGPR at 256/arg -> 128 cap,
// natural use ~124 (r4-proven), NO SPILLS (r7's (512,4) forced 64 VGPR and
// spilled ~1.1GB scratch traffic). 16 waves/CU = 4 waves/EU; LDS 66.5KB x2.
// Wave: 64 t (4 strips), 512 s in 64-chunks; barrier-free inner loop
// (direct-global frags, max-free exp2 softmax, per-wave XOR-swizzled LDS
// P-relayout). Epilogue: 2-way sg combine in LDS (2 barriers), sg0 writes
// fp32 Opart[si] + lpart[si]; attn_combine sums si partials.
// ---------------------------------------------------------------------------
__global__ __launch_bounds__(512, 2)
void attn_fused(const u16* __restrict__ Q, const u16* __restrict__ K,
                const u16* __restrict__ Vt, const float* __restrict__ negf,
                float* __restrict__ Opart, float* __restrict__ lpart)
{
    __shared__ char  Psh[65536];     // 8 waves x 8KB; reused for sg combine
    __shared__ float lsh[4][64];     // sg1 l partials: [tw][ts*16+m]

    const int tid = threadIdx.x;
    const int lane = tid & 63, w = tid >> 6;      // w 0..7
    const int sg = w >> 2, tw = w & 3;
    const int m = lane & 15, qd = lane >> 4;
    const int ti = blockIdx.x, si = blockIdx.y, bh = blockIdx.z;
    const int b = bh >> 3;

    const u16* Qp = Q + ((size_t)bh * TLEN + ti * 256) * 64;
    const u16* Kp = K + (size_t)bh * SLEN * 64;
    const u16* Vp = Vt + (size_t)bh * 64 * SLEN;
    const float* np = negf + (size_t)b * SLEN;

    // per-wave P buffer: row t=m (128B), 8B units XOR-swizzled by m
    const int wb = w * 8192 + m * 128;
    int waddr[4], ra0[2], ra1[2];
#pragma unroll
    for (int st = 0; st < 4; ++st) waddr[st] = wb + (((4 * st + qd) ^ m) << 3);
#pragma unroll
    for (int ks = 0; ks < 2; ++ks) {
        const int u0 = 8 * ks + 2 * qd;
        ra0[ks] = wb + ((u0 ^ m) << 3);
        ra1[ks] = wb + (((u0 + 1) ^ m) << 3);
    }

    bf16x8 qf[4][2];
#pragma unroll
    for (int ts = 0; ts < 4; ++ts)
#pragma unroll
        for (int kh = 0; kh < 2; ++kh)
            qf[ts][kh] = *(const bf16x8*)(Qp + (tw * 64 + ts * 16 + m) * 64 +
                                          32 * kh + 8 * qd);

    f32x4 O[4][4];
#pragma unroll
    for (int ts = 0; ts < 4; ++ts)
#pragma unroll
        for (int dt = 0; dt < 4; ++dt) O[ts][dt] = (f32x4){0.f, 0.f, 0.f, 0.f};
    float lr[4] = {0.f, 0.f, 0.f, 0.f};

    const int s_beg = si * 1024 + sg * 512;
    const u16* kp = Kp + (size_t)(s_beg + m) * 64 + 8 * qd;   // st*1024, kh*32 imm
    const u16* vp0 = Vp + (size_t)m * SLEN + s_beg + 8 * qd;  // ks*32 imm
    const u16* vp1 = vp0 + (size_t)16 * SLEN;
    const u16* vp2 = vp0 + (size_t)32 * SLEN;
    const u16* vp3 = vp0 + (size_t)48 * SLEN;
    const float* npp = np + s_beg + 4 * qd;                   // st*16 imm

#pragma unroll 1
    for (int c = 0; c < 512; c += 64) {
        bf16x8 kf[4][2];
        kf[0][0] = *(const bf16x8*)(kp + 0);
        kf[0][1] = *(const bf16x8*)(kp + 32);
        kf[1][0] = *(const bf16x8*)(kp + 1024);
        kf[1][1] = *(const bf16x8*)(kp + 1056);
        kf[2][0] = *(const bf16x8*)(kp + 2048);
        kf[2][1] = *(const bf16x8*)(kp + 2080);
        kf[3][0] = *(const bf16x8*)(kp + 3072);
        kf[3][1] = *(const bf16x8*)(kp + 3104);
        float4 ng[4];
        ng[0] = *(const float4*)(npp + 0);
        ng[1] = *(const float4*)(npp + 16);
        ng[2] = *(const float4*)(npp + 32);
        ng[3] = *(const float4*)(npp + 48);
        bf16x8 vf[4][2];
        vf[0][0] = *(const bf16x8*)(vp0 + 0);
        vf[0][1] = *(const bf16x8*)(vp0 + 32);
        vf[1][0] = *(const bf16x8*)(vp1 + 0);
        vf[1][1] = *(const bf16x8*)(vp1 + 32);
        vf[2][0] = *(const bf16x8*)(vp2 + 0);
        vf[2][1] = *(const bf16x8*)(vp2 + 32);
        vf[3][0] = *(const bf16x8*)(vp3 + 0);
        vf[3][1] = *(const bf16x8*)(vp3 + 32);

#pragma unroll
        for (int ts = 0; ts < 4; ++ts) {
            f32x4 S[4];
#pragma unroll
            for (int st = 0; st < 4; ++st) {
                f32x4 cc = (f32x4){0.f, 0.f, 0.f, 0.f};
                cc = __builtin_amdgcn_mfma_f32_16x16x32_bf16(kf[st][0], qf[ts][0], cc, 0, 0, 0);
                cc = __builtin_amdgcn_mfma_f32_16x16x32_bf16(kf[st][1], qf[ts][1], cc, 0, 0, 0);
                S[st] = cc;
            }
            float ls = 0.f;
#pragma unroll
            for (int st = 0; st < 4; ++st) {
                const float p0 = __builtin_amdgcn_exp2f(fmaf(S[st][0], SCL2, ng[st].x));
                const float p1 = __builtin_amdgcn_exp2f(fmaf(S[st][1], SCL2, ng[st].y));
                const float p2 = __builtin_amdgcn_exp2f(fmaf(S[st][2], SCL2, ng[st].z));
                const float p3 = __builtin_amdgcn_exp2f(fmaf(S[st][3], SCL2, ng[st].w));
                ls += (p0 + p1) + (p2 + p3);
                *(uint2*)&Psh[waddr[st] + ts * 2048] =
                    make_uint2(pk2(p0, p1), pk2(p2, p3));
            }
            lr[ts] += ls;
#pragma unroll
            for (int ks = 0; ks < 2; ++ks) {
                const uint2 r0 = *(uint2*)&Psh[ra0[ks] + ts * 2048];
                const uint2 r1 = *(uint2*)&Psh[ra1[ks] + ts * 2048];
                union { uint4 u; bf16x8 v; } bu;
                bu.u = make_uint4(r0.x, r0.y, r1.x, r1.y);
                O[ts][0] = __builtin_amdgcn_mfma_f32_16x16x32_bf16(vf[0][ks], bu.v, O[ts][0], 0, 0, 0);
                O[ts][1] = __builtin_amdgcn_mfma_f32_16x16x32_bf16(vf[1][ks], bu.v, O[ts][1], 0, 0, 0);
                O[ts][2] = __builtin_amdgcn_mfma_f32_16x16x32_bf16(vf[2][ks], bu.v, O[ts][2], 0, 0, 0);
                O[ts][3] = __builtin_amdgcn_mfma_f32_16x16x32_bf16(vf[3][ks], bu.v, O[ts][3], 0, 0, 0);
            }
        }
        kp += 4096; vp0 += 64; vp1 += 64; vp2 += 64; vp3 += 64; npp += 64;
    }

    // ---- epilogue: 2-way sg combine in LDS, then Opart/lpart write ----
    float lt[4];
#pragma unroll
    for (int ts = 0; ts < 4; ++ts) {
        float l = lr[ts];
        l += __shfl_xor(l, 16, 64);
        l += __shfl_xor(l, 32, 64);
        lt[ts] = l;
    }
    __syncthreads();                 // all waves done with their Psh regions
    float* combf = (float*)Psh;      // [tw][ts][dt][lane] f32x4
    if (sg == 1) {
#pragma unroll
        for (int ts = 0; ts < 4; ++ts) {
#pragma unroll
            for (int dt = 0; dt < 4; ++dt)
                *(f32x4*)&combf[tw * 4096 + ts * 1024 + dt * 256 + lane * 4] =
                    O[ts][dt];
            if (qd == 0) lsh[tw][ts * 16 + m] = lt[ts];
        }
    }
    __syncthreads();
    if (sg == 0) {
#pragma unroll
        for (int ts = 0; ts < 4; ++ts) {
            const float lsum = lt[ts] + lsh[tw][ts * 16 + m];
            const int t = ti * 256 + tw * 64 + ts * 16 + m;
            float* Ob = Opart + (((size_t)(si * 64 + bh)) * 512 + t) * 64;
#pragma unroll
            for (int dt = 0; dt < 4; ++dt) {
                const f32x4 v = *(f32x4*)&combf[tw * 4096 + ts * 1024 + dt * 256 + lane * 4];
                f32x4 o = O[ts][dt];
                o[0] += v[0]; o[1] += v[1]; o[2] += v[2]; o[3] += v[3];
                *(f32x4*)&Ob[16 * dt + 4 * qd] = o;
            }
            if (qd == 0)
                lpart[((size_t)(si * 64 + bh)) * 512 + t] = lsum;
        }
    }
}

// ---------------------------------------------------------------------------
// Combine split-S partials: ctx(B,T,512) bf16 = (sum O)/(sum l).
// ---------------------------------------------------------------------------
__global__ __launch_bounds__(256)
void attn_combine(const float* __restrict__ Opart, const float* __restrict__ lpart,
                  u16* __restrict__ ctx)
{
    const int gid = blockIdx.x * 256 + threadIdx.x;
    const int d4 = gid & 15, t = (gid >> 4) & 511, bh = gid >> 13;
    const int b = bh >> 3, h = bh & 7;
    float4 o = {0.f, 0.f, 0.f, 0.f}; float l = 0.f;
#pragma unroll
    for (int si = 0; si < SSPLIT; ++si) {
        const size_t base = ((size_t)(si * 64 + bh)) * 512 + t;
        l += lpart[base];
        const float4 v = *(const float4*)(Opart + base * 64 + d4 * 4);
        o.x += v.x; o.y += v.y; o.z += v.z; o.w += v.w;
    }
    const float r = 1.f / l;
    uint2 pk; pk.x = pkbf(o.x * r, o.y * r); pk.y = pkbf(o.z * r, o.w * r);
    *(uint2*)&ctx[((size_t)(b * 512 + t)) * 512 + h * 64 + d4 * 4] = pk;
}

// ---------------------------------------------------------------------------
extern "C" void kernel_launch(void* const* d_in, const int* in_sizes, int n_in,
                              void* d_out, int out_size, void* d_ws, size_t ws_size,
                              hipStream_t stream)
{
    const float* inputs  = (const float*)d_in[0];
    const float* targets = (const float*)d_in[1];
    const int*   mask    = (const int*)d_in[2];
    const float* Wq = (const float*)d_in[3];
    const float* bq = (const float*)d_in[4];
    const float* Wk = (const float*)d_in[5];
    const float* bk = (const float*)d_in[6];
    const float* Wv = (const float*)d_in[7];
    const float* bv = (const float*)d_in[8];
    const float* Wo = (const float*)d_in[9];
    const float* bo = (const float*)d_in[10];

    char* ws = (char*)d_ws;
    u16*   Xc    = (u16*)(ws);                            // 33,554,432 B
    u16*   Tc    = (u16*)(ws + 33554432);                 //  4,194,304
    u16*   Wc    = (u16*)(ws + 37748736);                 //  2,097,152
    float* negf  = (float*)(ws + 39845888);               //    131,072
    u16*   Qws   = (u16*)(ws + 39976960);                 //  4,194,304
    u16*   Kws   = (u16*)(ws + 44171264);                 // 33,554,432
    u16*   Vtws  = (u16*)(ws + 77725696);                 // 33,554,432
    u16*   Cws   = (u16*)(ws + 111280128);                //  4,194,304
    float* Opart = (float*)(ws + 115474432);              // 33,554,432
    float* lpart = (float*)(ws + 149028864);              //    524,288

    cvt_all<<<19488, 256, 0, stream>>>(inputs, targets, Wq, Wk, Wv, Wo, mask,
                                       Xc, Tc, Wc, negf);

    gemm_wxT<TLEN><<<dim3(32, 4),  256, 0, stream>>>(Wc,          Tc, bq, Qws);
    gemm_wxT<SLEN><<<dim3(256, 4), 256, 0, stream>>>(Wc + 262144, Xc, bk, Kws);
    gemm_bf16<2, SLEN><<<dim3(4, 256), 256, 0, stream>>>(Xc, Wc + 524288, bv, Vtws);

    attn_fused<<<dim3(2, 4, 64), 512, 0, stream>>>(Qws, Kws, Vtws, negf,
                                                   Opart, lpart);
    attn_combine<<<2048, 256, 0, stream>>>(Opart, lpart, Cws);

    gemm_bf16<0, TLEN><<<dim3(4, 32), 256, 0, stream>>>(Cws, Wc + 786432, bo,
                                                        (float*)d_out);
}